// Round 7
// baseline (239.934 us; speedup 1.0000x reference)
//
#include <hip/hip_runtime.h>
#include <hip/hip_cooperative_groups.h>
namespace cg = cooperative_groups;

#define NRAYS 4096
#define NSTEPS 160
#define NSAMP (NRAYS*NSTEPS)
#define GG 160
#define GG2 (GG*GG)
#define GG3 (GG*GG2)
#define GM 80
#define GM2 (GM*GM)

#define NEARV 0.05f
#define DISTV 0.00625f
#define SVAL 80.0f
#define ACT_SHIFT_C (-9.2102403669758813f)
#define INV2H 40.0f          // 1/(2*VOXEL_SIZE)
#define MASK_THRES_C 1e-3f
#define FAST_THRES_C 1e-7f

// normalized 5-tap gaussian, sigma=1
#define KW0 0.05448868454964295f
#define KW1 0.24420134200323332f
#define KW2 0.40261994689424750f

__device__ __forceinline__ float sigmf(float x){ return 1.0f/(1.0f+__expf(-x)); }
__device__ __forceinline__ float softplusf_(float x){ return (x>20.0f)? x : log1pf(__expf(x)); }

__device__ __forceinline__ void tricoord(float p, int Gx, int& i0, float& fr){
  float u = (p + 1.0f)*0.5f*(float)(Gx-1);
  u = fminf(fmaxf(u, 0.0f), (float)(Gx-1));
  int i = (int)floorf(u);
  i = min(max(i,0), Gx-2);
  i0 = i; fr = u - (float)i;
}

// ============ single fused cooperative kernel: smooth_yz -> march -> MLP ============
__global__ __launch_bounds__(256) void kfused(
  const float* __restrict__ ro, const float* __restrict__ rd,
  const float* __restrict__ vd, const int* __restrict__ em,
  const float* __restrict__ sdfg, const float* __restrict__ maskg,
  const float* __restrict__ offc, const float* __restrict__ emoc,
  const float* __restrict__ W0o, const float* __restrict__ b0o,
  const float* __restrict__ W1o, const float* __restrict__ b1o,
  const float* __restrict__ W2o, const float* __restrict__ b2o,
  const float* __restrict__ W0e, const float* __restrict__ b0e,
  const float* __restrict__ W1e, const float* __restrict__ b1e,
  const float* __restrict__ W2e, const float* __restrict__ b2e,
  float* __restrict__ Y, int* __restrict__ slist, float* __restrict__ sw,
  float* __restrict__ sgrad, int* __restrict__ cnt, float* __restrict__ out)
{
  // phase-1 LDS
  __shared__ float S[36][37];
  __shared__ float Tz[36][33];
  // phase-3 LDS
  __shared__ float X[8][80];
  __shared__ float H[8][132];
  __shared__ float H2[8][132];
  __shared__ float OUTB[8][3];
  __shared__ float WSH[8];
  __shared__ float GS[8][3];
  __shared__ int SSAMP[8];
  __shared__ int SEM[8];
  __shared__ int s_go;

  const int bid = blockIdx.x;
  const int t = threadIdx.x;
  cg::grid_group grid = cg::this_grid();

  // ---------------- init (block 0) ----------------
  if (bid == 0){
    for (int i = t; i < NRAYS*3; i += 256) out[i] = 0.0f;
    if (t == 0) *cnt = 0;
  }

  // ---------------- phase 1: fused y+z gaussian (zero-pad SAME), LDS tiled ----------------
  {
    const float kw[5] = {KW0,KW1,KW2,KW1,KW0};
    for (int tl = bid; tl < GG*25; tl += gridDim.x){
      __syncthreads();
      const int x  = tl / 25;
      const int tile = tl % 25;
      const int Y0 = (tile/5)*32, Z0 = (tile%5)*32;
      for (int i = t; i < 36*36; i += 256){
        int r = i/36, c = i - (i/36)*36;
        int y = Y0 + r - 2, z = Z0 + c - 2;
        float v = 0.0f;
        if (y>=0 && y<GG && z>=0 && z<GG) v = sdfg[(x*GG+y)*GG+z];
        S[r][c] = v;
      }
      __syncthreads();
      for (int i = t; i < 36*32; i += 256){
        int r = i >> 5, c = i & 31;
        float acc = 0.f;
        #pragma unroll
        for (int d=0; d<5; d++) acc += kw[d]*S[r][c+d];
        Tz[r][c] = acc;
      }
      __syncthreads();
      for (int i = t; i < 32*32; i += 256){
        int yy = i >> 5, c = i & 31;
        float acc = 0.f;
        #pragma unroll
        for (int d=0; d<5; d++) acc += kw[d]*Tz[yy+d][c];
        Y[(x*GG + Y0+yy)*GG + Z0 + c] = acc;
      }
    }
  }
  __threadfence();
  grid.sync();

  // ---------------- phase 2: serial per-ray march, x-conv on the fly ----------------
  {
    const int n = bid*256 + t;
    if (n < NRAYS){
      const float ox=ro[n*3+0], oy=ro[n*3+1], oz=ro[n*3+2];
      const float dx=rd[n*3+0], dy=rd[n*3+1], dz=rd[n*3+2];
      const float vx=vd[n*3+0], vy=vd[n*3+1], vz=vd[n*3+2];
      const float kwc[5] = {KW0,KW1,KW2,KW1,KW0};
      float T1=1.0f, T2=1.0f, cum=0.0f;
      for (int s=0; s<NSTEPS; s++){
        float tt = NEARV + DISTV*(float)s;
        float px = ox + dx*tt, py = oy + dy*tt, pz = oz + dz*tt;

        // mask-cache trilerp on 80^3 grid
        int mx,my,mz; float mfx,mfy,mfz;
        tricoord(px, GM, mx, mfx); tricoord(py, GM, my, mfy); tricoord(pz, GM, mz, mfz);
        int mid = (mx*GM + my)*GM + mz;
        float d000=maskg[mid],        d001=maskg[mid+1];
        float d010=maskg[mid+GM],     d011=maskg[mid+GM+1];
        float d100=maskg[mid+GM2],    d101=maskg[mid+GM2+1];
        float d110=maskg[mid+GM2+GM], d111=maskg[mid+GM2+GM+1];
        float m00 = d000 + (d001-d000)*mfz;
        float m01 = d010 + (d011-d010)*mfz;
        float m10 = d100 + (d101-d100)*mfz;
        float m11 = d110 + (d111-d110)*mfz;
        float m0 = m00 + (m01-m00)*mfy;
        float m1 = m10 + (m11-m10)*mfy;
        float dens = m0 + (m1-m0)*mfx;
        float malpha = 1.0f - __expf(-softplusf_(dens + ACT_SHIFT_C)*DISTV);

        int ix,iy,iz; float fx,fy,fz;
        tricoord(px, GG, ix, fx); tricoord(py, GG, iy, fy); tricoord(pz, GG, iz, fz);

        float R[2][2][8];
        #pragma unroll
        for (int jb=0;jb<2;jb++)
          #pragma unroll
          for (int jc=0;jc<2;jc++)
            #pragma unroll
            for (int j=0;j<8;j++){
              int a = ix-3+j;
              R[jb][jc][j] = (a>=0 && a<GG) ? Y[(a*GG + iy+jb)*GG + iz+jc] : 0.0f;
            }
        const bool hasym = (iy>=1), hasyp = (iy<=GG-3);
        const bool haszm = (iz>=1), haszp = (iz<=GG-3);
        float Eym[2][6], Eyp[2][6], Ezm[2][6], Ezp[2][6];
        #pragma unroll
        for (int jc=0;jc<2;jc++)
          #pragma unroll
          for (int j=0;j<6;j++){
            int a = ix-2+j;
            bool ax = (a>=0 && a<GG);
            Eym[jc][j] = (hasym && ax) ? Y[(a*GG + iy-1)*GG + iz+jc] : 0.0f;
            Eyp[jc][j] = (hasyp && ax) ? Y[(a*GG + iy+2)*GG + iz+jc] : 0.0f;
          }
        #pragma unroll
        for (int jb=0;jb<2;jb++)
          #pragma unroll
          for (int j=0;j<6;j++){
            int a = ix-2+j;
            bool ax = (a>=0 && a<GG);
            Ezm[jb][j] = (haszm && ax) ? Y[(a*GG + iy+jb)*GG + iz-1] : 0.0f;
            Ezp[jb][j] = (haszp && ax) ? Y[(a*GG + iy+jb)*GG + iz+2] : 0.0f;
          }

        float sdf=0.0f, gx=0.0f, gy=0.0f, gz=0.0f;
        #pragma unroll
        for (int ja=0;ja<2;ja++){
          #pragma unroll
          for (int jb=0;jb<2;jb++){
            #pragma unroll
            for (int jc=0;jc<2;jc++){
              float w = (ja?fx:1.0f-fx)*(jb?fy:1.0f-fy)*(jc?fz:1.0f-fz);
              const float* r = R[jb][jc];
              float s0=0.0f;
              #pragma unroll
              for (int t2=0;t2<5;t2++) s0 += kwc[t2]*r[ja+1+t2];
              sdf += w*s0;
              int a = ix+ja, b = iy+jb, c = iz+jc;
              if (a>=1 && a<=GG-2){
                float sp=0.0f, sm=0.0f;
                #pragma unroll
                for (int t2=0;t2<5;t2++){ sp += kwc[t2]*r[ja+2+t2]; sm += kwc[t2]*r[ja+t2]; }
                gx += w*INV2H*(sp-sm);
              }
              if (b>=1 && b<=GG-2){
                float acc=0.0f;
                if (jb==0){
                  const float* up = R[1][jc];
                  const float* dn = Eym[jc];
                  #pragma unroll
                  for (int t2=0;t2<5;t2++) acc += kwc[t2]*(up[ja+1+t2] - dn[ja+t2]);
                } else {
                  const float* up = Eyp[jc];
                  const float* dn = R[0][jc];
                  #pragma unroll
                  for (int t2=0;t2<5;t2++) acc += kwc[t2]*(up[ja+t2] - dn[ja+1+t2]);
                }
                gy += w*INV2H*acc;
              }
              if (c>=1 && c<=GG-2){
                float acc=0.0f;
                if (jc==0){
                  const float* up = R[jb][1];
                  const float* dn = Ezm[jb];
                  #pragma unroll
                  for (int t2=0;t2<5;t2++) acc += kwc[t2]*(up[ja+1+t2] - dn[ja+t2]);
                } else {
                  const float* up = Ezp[jb];
                  const float* dn = R[jb][0];
                  #pragma unroll
                  for (int t2=0;t2<5;t2++) acc += kwc[t2]*(up[ja+t2] - dn[ja+1+t2]);
                }
                gz += w*INV2H*acc;
              }
            }
          }
        }

        float tc = vx*gx + vy*gy + vz*gz;
        float icos = fminf(tc, 0.0f);
        float e = icos*DISTV*0.5f;
        float prev = sigmf((sdf - e)*SVAL);
        float nxt  = sigmf((sdf + e)*SVAL);
        float alpha = (prev - nxt + 1e-5f)/(prev + 1e-5f);
        alpha = fminf(fmaxf(alpha, 0.0f), 1.0f);
        if (!(malpha >= MASK_THRES_C)) alpha = 0.0f;

        float w1 = alpha*T1; T1 *= (1.0f - alpha);
        float a2 = (w1 > FAST_THRES_C) ? alpha : 0.0f;
        float wv = a2*T2;   T2 *= (1.0f - a2);
        cum += wv;
        if (wv > 0.0f){
          int pos = atomicAdd(cnt, 1);
          slist[pos] = n*NSTEPS + s;
          sw[pos] = wv;
          sgrad[pos*3+0]=gx; sgrad[pos*3+1]=gy; sgrad[pos*3+2]=gz;
        }
        if (T1 <= FAST_THRES_C) break;
      }
      out[NRAYS*3 + n] = T2;
      out[NRAYS*4 + n] = 1.0f - cum;
    }
  }
  __threadfence();
  grid.sync();

  // ---------------- phase 3: compacted MLP, one head per block parity ----------------
  {
    const int count = *cnt;
    const int head = bid & 1;
    const int cstride = gridDim.x >> 1;

    const float* W0 = head ? W0e : W0o;  const float* b0 = head ? b0e : b0o;
    const float* W1 = head ? W1e : W1o;  const float* b1 = head ? b1e : b1o;
    const float* W2 = head ? W2e : W2o;  const float* b2 = head ? b2e : b2o;
    const float* cg2 = head ? emoc : offc;
    const float4* W04 = (const float4*)W0;
    const float4* W14 = (const float4*)W1;

    const int sp   = t >> 5;     // sample 0..7
    const int lane = t & 31;     // 32 threads per sample, 4 outputs each

    for (int chunk = bid >> 1; chunk*8 < count; chunk += cstride) {
      const int base = chunk*8;
      if (t == 0) s_go = 0;
      if (t < 8) {
        int i = base + t;
        bool vld = (i < count);
        int samp = vld ? slist[i] : 0;
        SSAMP[t] = samp;
        WSH[t]   = vld ? sw[i] : 0.0f;
        GS[t][0] = vld ? sgrad[i*3+0] : 0.0f;
        GS[t][1] = vld ? sgrad[i*3+1] : 0.0f;
        GS[t][2] = vld ? sgrad[i*3+2] : 0.0f;
        SEM[t]   = vld ? em[samp/NSTEPS] : 0;
      }
      __syncthreads();
      if (t < 8) {
        bool live = (WSH[t] > 0.0f) && (head == 0 || SEM[t] != 0);
        if (live) s_go = 1;
      }
      __syncthreads();

      if (s_go) {
        // ---- features ----
        {
          const int s = t & 7;
          const int r = t >> 3;
          const int samp = SSAMP[s];
          const int n = samp / NSTEPS;
          const int step = samp - n*NSTEPS;
          const float tt = NEARV + DISTV*(float)step;
          const float px = ro[n*3+0] + rd[n*3+0]*tt;
          const float py = ro[n*3+1] + rd[n*3+1]*tt;
          const float pz = ro[n*3+2] + rd[n*3+2]*tt;
          if (r < 3) {
            int ix,iy,iz; float fx,fy,fz;
            tricoord(px, GG, ix, fx); tricoord(py, GG, iy, fy); tricoord(pz, GG, iz, fz);
            const float* g = cg2 + (size_t)r * GG3;
            const int id = (ix*GG + iy)*GG + iz;
            float v000=g[id],        v001=g[id+1];
            float v010=g[id+GG],     v011=g[id+GG+1];
            float v100=g[id+GG2],    v101=g[id+GG2+1];
            float v110=g[id+GG2+GG], v111=g[id+GG2+GG+1];
            float c00 = v000 + (v001-v000)*fz;
            float c01 = v010 + (v011-v010)*fz;
            float c10 = v100 + (v101-v100)*fz;
            float c11 = v110 + (v111-v110)*fz;
            float c0 = c00 + (c01-c00)*fy;
            float c1 = c10 + (c11-c10)*fy;
            X[s][r] = c0 + (c1-c0)*fx;
          } else if (r == 3) {
            X[s][3] = (px+1.0f)*0.5f;
            X[s][4] = (py+1.0f)*0.5f;
            X[s][5] = (pz+1.0f)*0.5f;
            float gx = GS[s][0], gy = GS[s][1], gz = GS[s][2];
            float inv = 1.0f/(sqrtf(gx*gx+gy*gy+gz*gz)+1e-5f);
            X[s][72] = gx*inv; X[s][73] = gy*inv; X[s][74] = gz*inv;
          } else if (r < 7) {
            const int a = r - 4;
            const float coord = (a==0)?px:((a==1)?py:pz);
            const float rxyz = (coord+1.0f)*0.5f;
            float fr = 1.0f;
            #pragma unroll
            for (int q = 0; q < 5; q++) {
              float e = rxyz*fr; fr *= 2.0f;
              X[s][6  + a*5 + q] = __sinf(e);
              X[s][21 + a*5 + q] = __cosf(e);
            }
          } else if (r < 10) {
            const int a = r - 7;
            const float v = vd[n*3+a];
            float fr = 1.0f;
            #pragma unroll
            for (int q = 0; q < 4; q++) {
              float e = v*fr; fr *= 2.0f;
              X[s][36 + a*4 + q] = e;
              X[s][48 + a*4 + q] = __sinf(e);
              X[s][60 + a*4 + q] = __cosf(e);
            }
          }
        }
        __syncthreads();

        // ---- layer 0: 75 -> 128 ----
        {
          float4 acc = ((const float4*)b0)[lane];
          #pragma unroll 5
          for (int k=0; k<75; k++){
            float x = X[sp][k];
            float4 w = W04[k*32 + lane];
            acc.x += x*w.x; acc.y += x*w.y; acc.z += x*w.z; acc.w += x*w.w;
          }
          H[sp][lane*4+0] = fmaxf(acc.x,0.0f);
          H[sp][lane*4+1] = fmaxf(acc.y,0.0f);
          H[sp][lane*4+2] = fmaxf(acc.z,0.0f);
          H[sp][lane*4+3] = fmaxf(acc.w,0.0f);
        }
        __syncthreads();

        // ---- layer 1: 128 -> 128 ----
        {
          float4 acc = ((const float4*)b1)[lane];
          #pragma unroll 8
          for (int k=0; k<128; k++){
            float x = H[sp][k];
            float4 w = W14[k*32 + lane];
            acc.x += x*w.x; acc.y += x*w.y; acc.z += x*w.z; acc.w += x*w.w;
          }
          H2[sp][lane*4+0] = fmaxf(acc.x,0.0f);
          H2[sp][lane*4+1] = fmaxf(acc.y,0.0f);
          H2[sp][lane*4+2] = fmaxf(acc.z,0.0f);
          H2[sp][lane*4+3] = fmaxf(acc.w,0.0f);
        }
        __syncthreads();

        // ---- layer 2: 128 -> 3, 32-lane shuffle reduce ----
        {
          float a0=0.0f, a1=0.0f, a2v=0.0f;
          #pragma unroll
          for (int i=0;i<4;i++){
            int k = lane*4+i;
            float h = H2[sp][k];
            a0  += h*W2[k*3+0];
            a1  += h*W2[k*3+1];
            a2v += h*W2[k*3+2];
          }
          #pragma unroll
          for (int d=16; d>=1; d>>=1){
            a0  += __shfl_down(a0,  d, 32);
            a1  += __shfl_down(a1,  d, 32);
            a2v += __shfl_down(a2v, d, 32);
          }
          if (lane == 0){
            OUTB[sp][0] = sigmf(a0  + b2[0]);
            OUTB[sp][1] = sigmf(a1  + b2[1]);
            OUTB[sp][2] = sigmf(a2v + b2[2]);
          }
        }
        __syncthreads();

        if (t < 24) {
          int s2 = t/3, c = t - s2*3;
          float w = WSH[s2];
          if (w > 0.0f && (head == 0 || SEM[s2] != 0)) {
            int n2 = SSAMP[s2]/NSTEPS;
            atomicAdd(&out[n2*3 + c], w * OUTB[s2][c]);
          }
        }
      }
      __syncthreads();
    }
  }
}

extern "C" void kernel_launch(void* const* d_in, const int* in_sizes, int n_in,
                              void* d_out, int out_size, void* d_ws, size_t ws_size,
                              hipStream_t stream) {
  const float* ro    = (const float*)d_in[0];
  const float* rd    = (const float*)d_in[1];
  const float* vd    = (const float*)d_in[2];
  const int*   em    = (const int*)d_in[3];
  const float* sdfg  = (const float*)d_in[4];
  const float* maskg = (const float*)d_in[5];
  const float* offc  = (const float*)d_in[6];
  const float* emoc  = (const float*)d_in[7];
  const float* W0o = (const float*)d_in[8];
  const float* b0o = (const float*)d_in[9];
  const float* W1o = (const float*)d_in[10];
  const float* b1o = (const float*)d_in[11];
  const float* W2o = (const float*)d_in[12];
  const float* b2o = (const float*)d_in[13];
  const float* W0e = (const float*)d_in[14];
  const float* b0e = (const float*)d_in[15];
  const float* W1e = (const float*)d_in[16];
  const float* b1e = (const float*)d_in[17];
  const float* W2e = (const float*)d_in[18];
  const float* b2e = (const float*)d_in[19];

  float* out = (float*)d_out;
  float* ws  = (float*)d_ws;
  float* Yb    = ws;                         // GG3 (yz-smoothed)
  float* swb   = ws + GG3;                   // NSAMP
  float* sgradb= swb + NSAMP;                // 3*NSAMP
  int*   slist = (int*)(sgradb + 3*(size_t)NSAMP);  // NSAMP
  int*   cnt   = slist + NSAMP;              // 1

  void* args[] = {
    &ro,&rd,&vd,&em,&sdfg,&maskg,&offc,&emoc,
    &W0o,&b0o,&W1o,&b1o,&W2o,&b2o,
    &W0e,&b0e,&W1e,&b1e,&W2e,&b2e,
    &Yb,&slist,&swb,&sgradb,&cnt,&out
  };
  hipLaunchCooperativeKernel((const void*)kfused, dim3(256), dim3(256),
                             args, 0, stream);
}

// Round 8
// 77.219 us; speedup vs baseline: 3.1072x; 3.1072x over previous
//
#include <hip/hip_runtime.h>

#define NRAYS 4096
#define NSTEPS 160
#define NSAMP (NRAYS*NSTEPS)
#define GG 160
#define GG2 (GG*GG)
#define GG3 (GG*GG2)
#define GM 80
#define GM2 (GM*GM)

#define NEARV 0.05f
#define DISTV 0.00625f
#define SVAL 80.0f
#define ACT_SHIFT_C (-9.2102403669758813f)
#define INV2H 40.0f          // 1/(2*VOXEL_SIZE)
#define MASK_THRES_C 1e-3f
#define FAST_THRES_C 1e-7f

// normalized 5-tap gaussian, sigma=1
#define KW0 0.05448868454964295f
#define KW1 0.24420134200323332f
#define KW2 0.40261994689424750f

__device__ __forceinline__ float sigmf(float x){ return 1.0f/(1.0f+__expf(-x)); }
__device__ __forceinline__ float softplusf_(float x){ return (x>20.0f)? x : log1pf(__expf(x)); }

__device__ __forceinline__ void tricoord(float p, int Gx, int& i0, float& fr){
  float u = (p + 1.0f)*0.5f*(float)(Gx-1);
  u = fminf(fmaxf(u, 0.0f), (float)(Gx-1));
  int i = (int)floorf(u);
  i = min(max(i,0), Gx-2);
  i0 = i; fr = u - (float)i;
}

// ---------------- fused y+z gaussian passes (zero-pad SAME), LDS tiled ----------------
// block 0 additionally zero-inits out rgb and cnt (stream-ordered before consumers).
__global__ __launch_bounds__(256) void ksmooth_yz(const float* __restrict__ in, float* __restrict__ out,
                                                  float* __restrict__ outbuf, int* __restrict__ cnt){
  __shared__ float S[36][37];
  __shared__ float Tz[36][33];
  const int bx = blockIdx.x;          // 160 * 25
  const int t = threadIdx.x;
  if (bx == 0){
    for (int i = t; i < NRAYS*3; i += 256) outbuf[i] = 0.0f;
    if (t == 0) *cnt = 0;
  }
  const int x  = bx / 25;
  const int tile = bx % 25;
  const int Y0 = (tile/5)*32, Z0 = (tile%5)*32;
  const float kw[5] = {KW0,KW1,KW2,KW1,KW0};
  for (int i = t; i < 36*36; i += 256){
    int r = i/36, c = i - (i/36)*36;
    int y = Y0 + r - 2, z = Z0 + c - 2;
    float v = 0.0f;
    if (y>=0 && y<GG && z>=0 && z<GG) v = in[(x*GG+y)*GG+z];
    S[r][c] = v;
  }
  __syncthreads();
  for (int i = t; i < 36*32; i += 256){
    int r = i >> 5, c = i & 31;
    float acc = 0.f;
    #pragma unroll
    for (int d=0; d<5; d++) acc += kw[d]*S[r][c+d];
    Tz[r][c] = acc;
  }
  __syncthreads();
  for (int i = t; i < 32*32; i += 256){
    int yy = i >> 5, c = i & 31;
    float acc = 0.f;
    #pragma unroll
    for (int d=0; d<5; d++) acc += kw[d]*Tz[yy+d][c];
    out[(x*GG + Y0+yy)*GG + Z0 + c] = acc;
  }
}

// ---------------- serial per-ray march on yz-smoothed grid, x-conv on the fly ----------------
// Early break exact: once T1 <= 1e-7, all later w1 = alpha*T1 <= 1e-7 fail strict > test.
__global__ __launch_bounds__(64) void kmarch(
  const float* __restrict__ ro, const float* __restrict__ rd,
  const float* __restrict__ vd, const float* __restrict__ maskg,
  const float* __restrict__ Y,
  int* __restrict__ slist, float* __restrict__ sw, float* __restrict__ sgrad,
  int* __restrict__ cnt, float* __restrict__ out)
{
  int n = blockIdx.x*64 + threadIdx.x;
  if (n >= NRAYS) return;
  const float ox=ro[n*3+0], oy=ro[n*3+1], oz=ro[n*3+2];
  const float dx=rd[n*3+0], dy=rd[n*3+1], dz=rd[n*3+2];
  const float vx=vd[n*3+0], vy=vd[n*3+1], vz=vd[n*3+2];
  const float kwc[5] = {KW0,KW1,KW2,KW1,KW0};
  float T1=1.0f, T2=1.0f, cum=0.0f;
  for (int s=0; s<NSTEPS; s++){
    float tt = NEARV + DISTV*(float)s;
    float px = ox + dx*tt, py = oy + dy*tt, pz = oz + dz*tt;

    // mask-cache trilerp on 80^3 grid
    int mx,my,mz; float mfx,mfy,mfz;
    tricoord(px, GM, mx, mfx); tricoord(py, GM, my, mfy); tricoord(pz, GM, mz, mfz);
    int mid = (mx*GM + my)*GM + mz;
    float d000=maskg[mid],        d001=maskg[mid+1];
    float d010=maskg[mid+GM],     d011=maskg[mid+GM+1];
    float d100=maskg[mid+GM2],    d101=maskg[mid+GM2+1];
    float d110=maskg[mid+GM2+GM], d111=maskg[mid+GM2+GM+1];
    float m00 = d000 + (d001-d000)*mfz;
    float m01 = d010 + (d011-d010)*mfz;
    float m10 = d100 + (d101-d100)*mfz;
    float m11 = d110 + (d111-d110)*mfz;
    float m0 = m00 + (m01-m00)*mfy;
    float m1 = m10 + (m11-m10)*mfy;
    float dens = m0 + (m1-m0)*mfx;
    float malpha = 1.0f - __expf(-softplusf_(dens + ACT_SHIFT_C)*DISTV);

    // sdf + gradient trilerp with on-the-fly x-conv over Y
    int ix,iy,iz; float fx,fy,fz;
    tricoord(px, GG, ix, fx); tricoord(py, GG, iy, fy); tricoord(pz, GG, iz, fz);

    float R[2][2][8];
    #pragma unroll
    for (int jb=0;jb<2;jb++)
      #pragma unroll
      for (int jc=0;jc<2;jc++)
        #pragma unroll
        for (int j=0;j<8;j++){
          int a = ix-3+j;
          R[jb][jc][j] = (a>=0 && a<GG) ? Y[(a*GG + iy+jb)*GG + iz+jc] : 0.0f;
        }
    const bool hasym = (iy>=1), hasyp = (iy<=GG-3);
    const bool haszm = (iz>=1), haszp = (iz<=GG-3);
    float Eym[2][6], Eyp[2][6], Ezm[2][6], Ezp[2][6];
    #pragma unroll
    for (int jc=0;jc<2;jc++)
      #pragma unroll
      for (int j=0;j<6;j++){
        int a = ix-2+j;
        bool ax = (a>=0 && a<GG);
        Eym[jc][j] = (hasym && ax) ? Y[(a*GG + iy-1)*GG + iz+jc] : 0.0f;
        Eyp[jc][j] = (hasyp && ax) ? Y[(a*GG + iy+2)*GG + iz+jc] : 0.0f;
      }
    #pragma unroll
    for (int jb=0;jb<2;jb++)
      #pragma unroll
      for (int j=0;j<6;j++){
        int a = ix-2+j;
        bool ax = (a>=0 && a<GG);
        Ezm[jb][j] = (haszm && ax) ? Y[(a*GG + iy+jb)*GG + iz-1] : 0.0f;
        Ezp[jb][j] = (haszp && ax) ? Y[(a*GG + iy+jb)*GG + iz+2] : 0.0f;
      }

    float sdf=0.0f, gx=0.0f, gy=0.0f, gz=0.0f;
    #pragma unroll
    for (int ja=0;ja<2;ja++){
      #pragma unroll
      for (int jb=0;jb<2;jb++){
        #pragma unroll
        for (int jc=0;jc<2;jc++){
          float w = (ja?fx:1.0f-fx)*(jb?fy:1.0f-fy)*(jc?fz:1.0f-fz);
          const float* r = R[jb][jc];
          float s0=0.0f;
          #pragma unroll
          for (int t2=0;t2<5;t2++) s0 += kwc[t2]*r[ja+1+t2];
          sdf += w*s0;
          int a = ix+ja, b = iy+jb, c = iz+jc;
          if (a>=1 && a<=GG-2){
            float sp=0.0f, sm=0.0f;
            #pragma unroll
            for (int t2=0;t2<5;t2++){ sp += kwc[t2]*r[ja+2+t2]; sm += kwc[t2]*r[ja+t2]; }
            gx += w*INV2H*(sp-sm);
          }
          if (b>=1 && b<=GG-2){
            float acc=0.0f;
            if (jb==0){
              const float* up = R[1][jc];
              const float* dn = Eym[jc];
              #pragma unroll
              for (int t2=0;t2<5;t2++) acc += kwc[t2]*(up[ja+1+t2] - dn[ja+t2]);
            } else {
              const float* up = Eyp[jc];
              const float* dn = R[0][jc];
              #pragma unroll
              for (int t2=0;t2<5;t2++) acc += kwc[t2]*(up[ja+t2] - dn[ja+1+t2]);
            }
            gy += w*INV2H*acc;
          }
          if (c>=1 && c<=GG-2){
            float acc=0.0f;
            if (jc==0){
              const float* up = R[jb][1];
              const float* dn = Ezm[jb];
              #pragma unroll
              for (int t2=0;t2<5;t2++) acc += kwc[t2]*(up[ja+1+t2] - dn[ja+t2]);
            } else {
              const float* up = Ezp[jb];
              const float* dn = R[jb][0];
              #pragma unroll
              for (int t2=0;t2<5;t2++) acc += kwc[t2]*(up[ja+t2] - dn[ja+1+t2]);
            }
            gz += w*INV2H*acc;
          }
        }
      }
    }

    float tc = vx*gx + vy*gy + vz*gz;
    float icos = fminf(tc, 0.0f);
    float e = icos*DISTV*0.5f;
    float prev = sigmf((sdf - e)*SVAL);
    float nxt  = sigmf((sdf + e)*SVAL);
    float alpha = (prev - nxt + 1e-5f)/(prev + 1e-5f);
    alpha = fminf(fmaxf(alpha, 0.0f), 1.0f);
    if (!(malpha >= MASK_THRES_C)) alpha = 0.0f;

    float w1 = alpha*T1; T1 *= (1.0f - alpha);
    float a2 = (w1 > FAST_THRES_C) ? alpha : 0.0f;
    float wv = a2*T2;   T2 *= (1.0f - a2);
    cum += wv;
    if (wv > 0.0f){
      int pos = atomicAdd(cnt, 1);
      slist[pos] = n*NSTEPS + s;
      sw[pos] = wv;
      sgrad[pos*3+0]=gx; sgrad[pos*3+1]=gy; sgrad[pos*3+2]=gz;
    }
    if (T1 <= FAST_THRES_C) break;
  }
  out[NRAYS*3 + n] = T2;
  out[NRAYS*4 + n] = 1.0f - cum;
}

// ---------------- compacted MLP with full weight set staged in LDS ----------------
// One head per block parity; per-block: stage W (106.5 KB) once, then process chunks.
// Arithmetic identical to kmlp3 (same order, same values, weights via LDS copies).
__global__ __launch_bounds__(256) void kmlp4(
  const float* __restrict__ ro, const float* __restrict__ rd,
  const float* __restrict__ vd, const int* __restrict__ em,
  const float* __restrict__ offc, const float* __restrict__ emoc,
  const int* __restrict__ slist, const float* __restrict__ sw,
  const float* __restrict__ sgrad, const int* __restrict__ cnt,
  const float* __restrict__ W0o, const float* __restrict__ b0o,
  const float* __restrict__ W1o, const float* __restrict__ b1o,
  const float* __restrict__ W2o, const float* __restrict__ b2o,
  const float* __restrict__ W0e, const float* __restrict__ b0e,
  const float* __restrict__ W1e, const float* __restrict__ b1e,
  const float* __restrict__ W2e, const float* __restrict__ b2e,
  float* __restrict__ out)
{
  __shared__ float4 W0s[75*32];    // 38400 B
  __shared__ float4 W1s[128*32];   // 65536 B
  __shared__ float  W2s[128*3];    // 1536 B
  __shared__ float  b0s[128], b1s[128], b2s[3];
  __shared__ float X[8][80];
  __shared__ float H[8][132];
  __shared__ float H2[8][132];
  __shared__ float OUTB[8][3];
  __shared__ float WSH[8];
  __shared__ float GS[8][3];
  __shared__ int SSAMP[8];
  __shared__ int SEM[8];
  __shared__ int s_go;

  const int t = threadIdx.x;
  const int count = *cnt;
  const int head = blockIdx.x & 1;
  const int cstride = gridDim.x >> 1;

  const float* W0 = head ? W0e : W0o;  const float* b0 = head ? b0e : b0o;
  const float* W1 = head ? W1e : W1o;  const float* b1 = head ? b1e : b1o;
  const float* W2 = head ? W2e : W2o;  const float* b2 = head ? b2e : b2o;
  const float* cg = head ? emoc : offc;

  // ---- stage weights into LDS ----
  {
    const float4* g0 = (const float4*)W0;
    for (int i = t; i < 75*32; i += 256) W0s[i] = g0[i];
    const float4* g1 = (const float4*)W1;
    for (int i = t; i < 128*32; i += 256) W1s[i] = g1[i];
    for (int i = t; i < 128*3; i += 256) W2s[i] = W2[i];
    if (t < 128){ b0s[t] = b0[t]; b1s[t] = b1[t]; }
    if (t < 3) b2s[t] = b2[t];
  }
  __syncthreads();

  const int sp   = t >> 5;     // sample 0..7
  const int lane = t & 31;     // 32 threads per sample, 4 outputs each

  for (int chunk = blockIdx.x >> 1; chunk*8 < count; chunk += cstride) {
    const int base = chunk*8;
    if (t == 0) s_go = 0;
    if (t < 8) {
      int i = base + t;
      bool vld = (i < count);
      int samp = vld ? slist[i] : 0;
      SSAMP[t] = samp;
      WSH[t]   = vld ? sw[i] : 0.0f;
      GS[t][0] = vld ? sgrad[i*3+0] : 0.0f;
      GS[t][1] = vld ? sgrad[i*3+1] : 0.0f;
      GS[t][2] = vld ? sgrad[i*3+2] : 0.0f;
      SEM[t]   = vld ? em[samp/NSTEPS] : 0;
    }
    __syncthreads();
    if (t < 8) {
      bool live = (WSH[t] > 0.0f) && (head == 0 || SEM[t] != 0);
      if (live) s_go = 1;
    }
    __syncthreads();

    if (s_go) {
      // ---- features: s = t&7 sample, r = t>>3 group ----
      {
        const int s = t & 7;
        const int r = t >> 3;
        const int samp = SSAMP[s];
        const int n = samp / NSTEPS;
        const int step = samp - n*NSTEPS;
        const float tt = NEARV + DISTV*(float)step;
        const float px = ro[n*3+0] + rd[n*3+0]*tt;
        const float py = ro[n*3+1] + rd[n*3+1]*tt;
        const float pz = ro[n*3+2] + rd[n*3+2]*tt;
        if (r < 3) {
          int ix,iy,iz; float fx,fy,fz;
          tricoord(px, GG, ix, fx); tricoord(py, GG, iy, fy); tricoord(pz, GG, iz, fz);
          const float* g = cg + (size_t)r * GG3;
          const int id = (ix*GG + iy)*GG + iz;
          float v000=g[id],        v001=g[id+1];
          float v010=g[id+GG],     v011=g[id+GG+1];
          float v100=g[id+GG2],    v101=g[id+GG2+1];
          float v110=g[id+GG2+GG], v111=g[id+GG2+GG+1];
          float c00 = v000 + (v001-v000)*fz;
          float c01 = v010 + (v011-v010)*fz;
          float c10 = v100 + (v101-v100)*fz;
          float c11 = v110 + (v111-v110)*fz;
          float c0 = c00 + (c01-c00)*fy;
          float c1 = c10 + (c11-c10)*fy;
          X[s][r] = c0 + (c1-c0)*fx;
        } else if (r == 3) {
          X[s][3] = (px+1.0f)*0.5f;
          X[s][4] = (py+1.0f)*0.5f;
          X[s][5] = (pz+1.0f)*0.5f;
          float gx = GS[s][0], gy = GS[s][1], gz = GS[s][2];
          float inv = 1.0f/(sqrtf(gx*gx+gy*gy+gz*gz)+1e-5f);
          X[s][72] = gx*inv; X[s][73] = gy*inv; X[s][74] = gz*inv;
        } else if (r < 7) {
          const int a = r - 4;
          const float coord = (a==0)?px:((a==1)?py:pz);
          const float rxyz = (coord+1.0f)*0.5f;
          float fr = 1.0f;
          #pragma unroll
          for (int q = 0; q < 5; q++) {
            float e = rxyz*fr; fr *= 2.0f;
            X[s][6  + a*5 + q] = __sinf(e);
            X[s][21 + a*5 + q] = __cosf(e);
          }
        } else if (r < 10) {
          const int a = r - 7;
          const float v = vd[n*3+a];
          float fr = 1.0f;
          #pragma unroll
          for (int q = 0; q < 4; q++) {
            float e = v*fr; fr *= 2.0f;
            X[s][36 + a*4 + q] = e;
            X[s][48 + a*4 + q] = __sinf(e);
            X[s][60 + a*4 + q] = __cosf(e);
          }
        }
      }
      __syncthreads();

      // ---- layer 0: 75 -> 128 (weights from LDS) ----
      {
        float4 acc = make_float4(b0s[lane*4+0], b0s[lane*4+1], b0s[lane*4+2], b0s[lane*4+3]);
        #pragma unroll 5
        for (int k=0; k<75; k++){
          float x = X[sp][k];
          float4 w = W0s[k*32 + lane];
          acc.x += x*w.x; acc.y += x*w.y; acc.z += x*w.z; acc.w += x*w.w;
        }
        H[sp][lane*4+0] = fmaxf(acc.x,0.0f);
        H[sp][lane*4+1] = fmaxf(acc.y,0.0f);
        H[sp][lane*4+2] = fmaxf(acc.z,0.0f);
        H[sp][lane*4+3] = fmaxf(acc.w,0.0f);
      }
      __syncthreads();

      // ---- layer 1: 128 -> 128 (weights from LDS) ----
      {
        float4 acc = make_float4(b1s[lane*4+0], b1s[lane*4+1], b1s[lane*4+2], b1s[lane*4+3]);
        #pragma unroll 8
        for (int k=0; k<128; k++){
          float x = H[sp][k];
          float4 w = W1s[k*32 + lane];
          acc.x += x*w.x; acc.y += x*w.y; acc.z += x*w.z; acc.w += x*w.w;
        }
        H2[sp][lane*4+0] = fmaxf(acc.x,0.0f);
        H2[sp][lane*4+1] = fmaxf(acc.y,0.0f);
        H2[sp][lane*4+2] = fmaxf(acc.z,0.0f);
        H2[sp][lane*4+3] = fmaxf(acc.w,0.0f);
      }
      __syncthreads();

      // ---- layer 2: 128 -> 3, 32-lane shuffle reduce ----
      {
        float a0=0.0f, a1=0.0f, a2v=0.0f;
        #pragma unroll
        for (int i=0;i<4;i++){
          int k = lane*4+i;
          float h = H2[sp][k];
          a0  += h*W2s[k*3+0];
          a1  += h*W2s[k*3+1];
          a2v += h*W2s[k*3+2];
        }
        #pragma unroll
        for (int d=16; d>=1; d>>=1){
          a0  += __shfl_down(a0,  d, 32);
          a1  += __shfl_down(a1,  d, 32);
          a2v += __shfl_down(a2v, d, 32);
        }
        if (lane == 0){
          OUTB[sp][0] = sigmf(a0  + b2s[0]);
          OUTB[sp][1] = sigmf(a1  + b2s[1]);
          OUTB[sp][2] = sigmf(a2v + b2s[2]);
        }
      }
      __syncthreads();

      if (t < 24) {
        int s2 = t/3, c = t - s2*3;
        float w = WSH[s2];
        if (w > 0.0f && (head == 0 || SEM[s2] != 0)) {
          int n2 = SSAMP[s2]/NSTEPS;
          atomicAdd(&out[n2*3 + c], w * OUTB[s2][c]);
        }
      }
    }
    __syncthreads();
  }
}

extern "C" void kernel_launch(void* const* d_in, const int* in_sizes, int n_in,
                              void* d_out, int out_size, void* d_ws, size_t ws_size,
                              hipStream_t stream) {
  const float* ro    = (const float*)d_in[0];
  const float* rd    = (const float*)d_in[1];
  const float* vd    = (const float*)d_in[2];
  const int*   em    = (const int*)d_in[3];
  const float* sdfg  = (const float*)d_in[4];
  const float* maskg = (const float*)d_in[5];
  const float* offc  = (const float*)d_in[6];
  const float* emoc  = (const float*)d_in[7];
  const float* W0o = (const float*)d_in[8];
  const float* b0o = (const float*)d_in[9];
  const float* W1o = (const float*)d_in[10];
  const float* b1o = (const float*)d_in[11];
  const float* W2o = (const float*)d_in[12];
  const float* b2o = (const float*)d_in[13];
  const float* W0e = (const float*)d_in[14];
  const float* b0e = (const float*)d_in[15];
  const float* W1e = (const float*)d_in[16];
  const float* b1e = (const float*)d_in[17];
  const float* W2e = (const float*)d_in[18];
  const float* b2e = (const float*)d_in[19];

  float* out = (float*)d_out;
  float* ws  = (float*)d_ws;
  float* Yb    = ws;                         // GG3 (yz-smoothed)
  float* swb   = ws + GG3;                   // NSAMP
  float* sgradb= swb + NSAMP;                // 3*NSAMP
  int*   slist = (int*)(sgradb + 3*(size_t)NSAMP);  // NSAMP
  int*   cnt   = slist + NSAMP;              // 1

  ksmooth_yz<<<GG*25, 256, 0, stream>>>(sdfg, Yb, out, cnt);

  kmarch<<<NRAYS/64, 64, 0, stream>>>(ro, rd, vd, maskg, Yb,
                                      slist, swb, sgradb, cnt, out);

  kmlp4<<<512, 256, 0, stream>>>(ro, rd, vd, em, offc, emoc,
                                 slist, swb, sgradb, cnt,
                                 W0o,b0o,W1o,b1o,W2o,b2o,
                                 W0e,b0e,W1e,b1e,W2e,b2e, out);
}

// Round 9
// 54.291 us; speedup vs baseline: 4.4194x; 1.4223x over previous
//
#include <hip/hip_runtime.h>

#define NRAYS 4096
#define NSTEPS 160
#define NSAMP (NRAYS*NSTEPS)
#define GG 160
#define GG2 (GG*GG)
#define GG3 (GG*GG2)
#define GM 80
#define GM2 (GM*GM)

#define NEARV 0.05f
#define DISTV 0.00625f
#define SVAL 80.0f
#define ACT_SHIFT_C (-9.2102403669758813f)
#define INV2H 40.0f          // 1/(2*VOXEL_SIZE)
#define MASK_THRES_C 1e-3f
#define FAST_THRES_C 1e-7f

// normalized 5-tap gaussian, sigma=1
#define KW0 0.05448868454964295f
#define KW1 0.24420134200323332f
#define KW2 0.40261994689424750f

__device__ __forceinline__ float sigmf(float x){ return 1.0f/(1.0f+__expf(-x)); }
__device__ __forceinline__ float softplusf_(float x){ return (x>20.0f)? x : log1pf(__expf(x)); }

__device__ __forceinline__ void tricoord(float p, int Gx, int& i0, float& fr){
  float u = (p + 1.0f)*0.5f*(float)(Gx-1);
  u = fminf(fmaxf(u, 0.0f), (float)(Gx-1));
  int i = (int)floorf(u);
  i = min(max(i,0), Gx-2);
  i0 = i; fr = u - (float)i;
}

// ---------------- fused y+z gaussian passes (zero-pad SAME), LDS tiled ----------------
// block 0 additionally zero-inits out rgb and cnt (stream-ordered before consumers).
__global__ __launch_bounds__(256) void ksmooth_yz(const float* __restrict__ in, float* __restrict__ out,
                                                  float* __restrict__ outbuf, int* __restrict__ cnt){
  __shared__ float S[36][37];
  __shared__ float Tz[36][33];
  const int bx = blockIdx.x;          // 160 * 25
  const int t = threadIdx.x;
  if (bx == 0){
    for (int i = t; i < NRAYS*3; i += 256) outbuf[i] = 0.0f;
    if (t == 0) *cnt = 0;
  }
  const int x  = bx / 25;
  const int tile = bx % 25;
  const int Y0 = (tile/5)*32, Z0 = (tile%5)*32;
  const float kw[5] = {KW0,KW1,KW2,KW1,KW0};
  for (int i = t; i < 36*36; i += 256){
    int r = i/36, c = i - (i/36)*36;
    int y = Y0 + r - 2, z = Z0 + c - 2;
    float v = 0.0f;
    if (y>=0 && y<GG && z>=0 && z<GG) v = in[(x*GG+y)*GG+z];
    S[r][c] = v;
  }
  __syncthreads();
  for (int i = t; i < 36*32; i += 256){
    int r = i >> 5, c = i & 31;
    float acc = 0.f;
    #pragma unroll
    for (int d=0; d<5; d++) acc += kw[d]*S[r][c+d];
    Tz[r][c] = acc;
  }
  __syncthreads();
  for (int i = t; i < 32*32; i += 256){
    int yy = i >> 5, c = i & 31;
    float acc = 0.f;
    #pragma unroll
    for (int d=0; d<5; d++) acc += kw[d]*Tz[yy+d][c];
    out[(x*GG + Y0+yy)*GG + Z0 + c] = acc;
  }
}

// ---------------- serial per-ray march on yz-smoothed grid, x-conv on the fly ----------------
// Early break exact: once T1 <= 1e-7, all later w1 = alpha*T1 <= 1e-7 fail strict > test.
__global__ __launch_bounds__(64) void kmarch(
  const float* __restrict__ ro, const float* __restrict__ rd,
  const float* __restrict__ vd, const float* __restrict__ maskg,
  const float* __restrict__ Y,
  int* __restrict__ slist, float* __restrict__ sw, float* __restrict__ sgrad,
  int* __restrict__ cnt, float* __restrict__ out)
{
  int n = blockIdx.x*64 + threadIdx.x;
  if (n >= NRAYS) return;
  const float ox=ro[n*3+0], oy=ro[n*3+1], oz=ro[n*3+2];
  const float dx=rd[n*3+0], dy=rd[n*3+1], dz=rd[n*3+2];
  const float vx=vd[n*3+0], vy=vd[n*3+1], vz=vd[n*3+2];
  const float kwc[5] = {KW0,KW1,KW2,KW1,KW0};
  float T1=1.0f, T2=1.0f, cum=0.0f;
  for (int s=0; s<NSTEPS; s++){
    float tt = NEARV + DISTV*(float)s;
    float px = ox + dx*tt, py = oy + dy*tt, pz = oz + dz*tt;

    // mask-cache trilerp on 80^3 grid
    int mx,my,mz; float mfx,mfy,mfz;
    tricoord(px, GM, mx, mfx); tricoord(py, GM, my, mfy); tricoord(pz, GM, mz, mfz);
    int mid = (mx*GM + my)*GM + mz;
    float d000=maskg[mid],        d001=maskg[mid+1];
    float d010=maskg[mid+GM],     d011=maskg[mid+GM+1];
    float d100=maskg[mid+GM2],    d101=maskg[mid+GM2+1];
    float d110=maskg[mid+GM2+GM], d111=maskg[mid+GM2+GM+1];
    float m00 = d000 + (d001-d000)*mfz;
    float m01 = d010 + (d011-d010)*mfz;
    float m10 = d100 + (d101-d100)*mfz;
    float m11 = d110 + (d111-d110)*mfz;
    float m0 = m00 + (m01-m00)*mfy;
    float m1 = m10 + (m11-m10)*mfy;
    float dens = m0 + (m1-m0)*mfx;
    float malpha = 1.0f - __expf(-softplusf_(dens + ACT_SHIFT_C)*DISTV);

    // sdf + gradient trilerp with on-the-fly x-conv over Y
    int ix,iy,iz; float fx,fy,fz;
    tricoord(px, GG, ix, fx); tricoord(py, GG, iy, fy); tricoord(pz, GG, iz, fz);

    float R[2][2][8];
    #pragma unroll
    for (int jb=0;jb<2;jb++)
      #pragma unroll
      for (int jc=0;jc<2;jc++)
        #pragma unroll
        for (int j=0;j<8;j++){
          int a = ix-3+j;
          R[jb][jc][j] = (a>=0 && a<GG) ? Y[(a*GG + iy+jb)*GG + iz+jc] : 0.0f;
        }
    const bool hasym = (iy>=1), hasyp = (iy<=GG-3);
    const bool haszm = (iz>=1), haszp = (iz<=GG-3);
    float Eym[2][6], Eyp[2][6], Ezm[2][6], Ezp[2][6];
    #pragma unroll
    for (int jc=0;jc<2;jc++)
      #pragma unroll
      for (int j=0;j<6;j++){
        int a = ix-2+j;
        bool ax = (a>=0 && a<GG);
        Eym[jc][j] = (hasym && ax) ? Y[(a*GG + iy-1)*GG + iz+jc] : 0.0f;
        Eyp[jc][j] = (hasyp && ax) ? Y[(a*GG + iy+2)*GG + iz+jc] : 0.0f;
      }
    #pragma unroll
    for (int jb=0;jb<2;jb++)
      #pragma unroll
      for (int j=0;j<6;j++){
        int a = ix-2+j;
        bool ax = (a>=0 && a<GG);
        Ezm[jb][j] = (haszm && ax) ? Y[(a*GG + iy+jb)*GG + iz-1] : 0.0f;
        Ezp[jb][j] = (haszp && ax) ? Y[(a*GG + iy+jb)*GG + iz+2] : 0.0f;
      }

    float sdf=0.0f, gx=0.0f, gy=0.0f, gz=0.0f;
    #pragma unroll
    for (int ja=0;ja<2;ja++){
      #pragma unroll
      for (int jb=0;jb<2;jb++){
        #pragma unroll
        for (int jc=0;jc<2;jc++){
          float w = (ja?fx:1.0f-fx)*(jb?fy:1.0f-fy)*(jc?fz:1.0f-fz);
          const float* r = R[jb][jc];
          float s0=0.0f;
          #pragma unroll
          for (int t2=0;t2<5;t2++) s0 += kwc[t2]*r[ja+1+t2];
          sdf += w*s0;
          int a = ix+ja, b = iy+jb, c = iz+jc;
          if (a>=1 && a<=GG-2){
            float sp=0.0f, sm=0.0f;
            #pragma unroll
            for (int t2=0;t2<5;t2++){ sp += kwc[t2]*r[ja+2+t2]; sm += kwc[t2]*r[ja+t2]; }
            gx += w*INV2H*(sp-sm);
          }
          if (b>=1 && b<=GG-2){
            float acc=0.0f;
            if (jb==0){
              const float* up = R[1][jc];
              const float* dn = Eym[jc];
              #pragma unroll
              for (int t2=0;t2<5;t2++) acc += kwc[t2]*(up[ja+1+t2] - dn[ja+t2]);
            } else {
              const float* up = Eyp[jc];
              const float* dn = R[0][jc];
              #pragma unroll
              for (int t2=0;t2<5;t2++) acc += kwc[t2]*(up[ja+t2] - dn[ja+1+t2]);
            }
            gy += w*INV2H*acc;
          }
          if (c>=1 && c<=GG-2){
            float acc=0.0f;
            if (jc==0){
              const float* up = R[jb][1];
              const float* dn = Ezm[jb];
              #pragma unroll
              for (int t2=0;t2<5;t2++) acc += kwc[t2]*(up[ja+1+t2] - dn[ja+t2]);
            } else {
              const float* up = Ezp[jb];
              const float* dn = R[jb][0];
              #pragma unroll
              for (int t2=0;t2<5;t2++) acc += kwc[t2]*(up[ja+t2] - dn[ja+1+t2]);
            }
            gz += w*INV2H*acc;
          }
        }
      }
    }

    float tc = vx*gx + vy*gy + vz*gz;
    float icos = fminf(tc, 0.0f);
    float e = icos*DISTV*0.5f;
    float prev = sigmf((sdf - e)*SVAL);
    float nxt  = sigmf((sdf + e)*SVAL);
    float alpha = (prev - nxt + 1e-5f)/(prev + 1e-5f);
    alpha = fminf(fmaxf(alpha, 0.0f), 1.0f);
    if (!(malpha >= MASK_THRES_C)) alpha = 0.0f;

    float w1 = alpha*T1; T1 *= (1.0f - alpha);
    float a2 = (w1 > FAST_THRES_C) ? alpha : 0.0f;
    float wv = a2*T2;   T2 *= (1.0f - a2);
    cum += wv;
    if (wv > 0.0f){
      int pos = atomicAdd(cnt, 1);
      slist[pos] = n*NSTEPS + s;
      sw[pos] = wv;
      sgrad[pos*3+0]=gx; sgrad[pos*3+1]=gy; sgrad[pos*3+2]=gz;
    }
    if (T1 <= FAST_THRES_C) break;
  }
  out[NRAYS*3 + n] = T2;
  out[NRAYS*4 + n] = 1.0f - cum;
}

// ---------------- kmlp5: 32 samples/block, 4 samples x 4 outputs per thread ----------------
// Weights from L2 (no staging). K-loop in batches of 4: 4 weight float4 loads +
// 4 ds_read_b128 of activations + 64 FMAs -> 16 FLOP per weight load.
// Arithmetic per output is the same ordered k-sum as kmlp3 (fp32, bit-identical).
__global__ __launch_bounds__(256) void kmlp5(
  const float* __restrict__ ro, const float* __restrict__ rd,
  const float* __restrict__ vd, const int* __restrict__ em,
  const float* __restrict__ offc, const float* __restrict__ emoc,
  const int* __restrict__ slist, const float* __restrict__ sw,
  const float* __restrict__ sgrad, const int* __restrict__ cnt,
  const float* __restrict__ W0o, const float* __restrict__ b0o,
  const float* __restrict__ W1o, const float* __restrict__ b1o,
  const float* __restrict__ W2o, const float* __restrict__ b2o,
  const float* __restrict__ W0e, const float* __restrict__ b0e,
  const float* __restrict__ W1e, const float* __restrict__ b1e,
  const float* __restrict__ W2e, const float* __restrict__ b2e,
  float* __restrict__ out)
{
  __shared__ float X[32][80];      // [0:3] color, rest shared features
  __shared__ float H[32][132];
  __shared__ float H2[32][132];
  __shared__ float OUTB[32][3];
  __shared__ float WSH[32];
  __shared__ float GS[32][3];
  __shared__ int SSAMP[32];
  __shared__ int SEM[32];
  __shared__ int s_go;

  const int t = threadIdx.x;
  const int count = *cnt;
  const int head = blockIdx.x & 1;
  const int cstride = gridDim.x >> 1;

  const float* W0 = head ? W0e : W0o;  const float* b0 = head ? b0e : b0o;
  const float* W1 = head ? W1e : W1o;  const float* b1 = head ? b1e : b1o;
  const float* W2 = head ? W2e : W2o;  const float* b2 = head ? b2e : b2o;
  const float* cg = head ? emoc : offc;
  const float4* W04 = (const float4*)W0;
  const float4* W14 = (const float4*)W1;

  const int lane = t & 31;     // output group: outputs 4*lane .. 4*lane+3
  const int sg   = t >> 5;     // sample group: samples 4*sg .. 4*sg+3

  for (int chunk = blockIdx.x >> 1; chunk*32 < count; chunk += cstride) {
    const int base = chunk*32;
    if (t == 0) s_go = 0;
    if (t < 32) {
      int i = base + t;
      bool vld = (i < count);
      int samp = vld ? slist[i] : 0;
      SSAMP[t] = samp;
      WSH[t]   = vld ? sw[i] : 0.0f;
      GS[t][0] = vld ? sgrad[i*3+0] : 0.0f;
      GS[t][1] = vld ? sgrad[i*3+1] : 0.0f;
      GS[t][2] = vld ? sgrad[i*3+2] : 0.0f;
      SEM[t]   = vld ? em[samp/NSTEPS] : 0;
    }
    __syncthreads();
    if (t < 32) {
      bool live = (WSH[t] > 0.0f) && (head == 0 || SEM[t] != 0);
      if (live) s_go = 1;
    }
    __syncthreads();

    if (s_go) {
      // ---- features: s = t&31 sample, r = t>>5 group (0..7) ----
      {
        const int s = t & 31;
        const int r = t >> 5;
        const int samp = SSAMP[s];
        const int n = samp / NSTEPS;
        const int step = samp - n*NSTEPS;
        const float tt = NEARV + DISTV*(float)step;
        const float px = ro[n*3+0] + rd[n*3+0]*tt;
        const float py = ro[n*3+1] + rd[n*3+1]*tt;
        const float pz = ro[n*3+2] + rd[n*3+2]*tt;
        if (r < 3) {
          int ix,iy,iz; float fx,fy,fz;
          tricoord(px, GG, ix, fx); tricoord(py, GG, iy, fy); tricoord(pz, GG, iz, fz);
          const float* g = cg + (size_t)r * GG3;
          const int id = (ix*GG + iy)*GG + iz;
          float v000=g[id],        v001=g[id+1];
          float v010=g[id+GG],     v011=g[id+GG+1];
          float v100=g[id+GG2],    v101=g[id+GG2+1];
          float v110=g[id+GG2+GG], v111=g[id+GG2+GG+1];
          float c00 = v000 + (v001-v000)*fz;
          float c01 = v010 + (v011-v010)*fz;
          float c10 = v100 + (v101-v100)*fz;
          float c11 = v110 + (v111-v110)*fz;
          float c0 = c00 + (c01-c00)*fy;
          float c1 = c10 + (c11-c10)*fy;
          X[s][r] = c0 + (c1-c0)*fx;
        } else if (r == 3) {
          X[s][3] = (px+1.0f)*0.5f;
          X[s][4] = (py+1.0f)*0.5f;
          X[s][5] = (pz+1.0f)*0.5f;
          float gx = GS[s][0], gy = GS[s][1], gz = GS[s][2];
          float inv = 1.0f/(sqrtf(gx*gx+gy*gy+gz*gz)+1e-5f);
          X[s][72] = gx*inv; X[s][73] = gy*inv; X[s][74] = gz*inv;
          X[s][75] = 0.0f; X[s][76] = 0.0f; X[s][77] = 0.0f; X[s][78] = 0.0f; X[s][79] = 0.0f;
        } else if (r < 7) {
          const int a = r - 4;
          const float coord = (a==0)?px:((a==1)?py:pz);
          const float rxyz = (coord+1.0f)*0.5f;
          float fr = 1.0f;
          #pragma unroll
          for (int q = 0; q < 5; q++) {
            float e = rxyz*fr; fr *= 2.0f;
            X[s][6  + a*5 + q] = __sinf(e);
            X[s][21 + a*5 + q] = __cosf(e);
          }
          const float v = vd[n*3+a];
          float fr2 = 1.0f;
          #pragma unroll
          for (int q = 0; q < 4; q++) {
            float e = v*fr2; fr2 *= 2.0f;
            X[s][36 + a*4 + q] = e;
            X[s][48 + a*4 + q] = __sinf(e);
            X[s][60 + a*4 + q] = __cosf(e);
          }
        }
      }
      __syncthreads();

      // ---- layer 0: 75 -> 128, batches of 4 k ----
      {
        const float4 bb = ((const float4*)b0)[lane];
        float4 a0 = bb, a1 = bb, a2 = bb, a3 = bb;
        const int s0 = sg*4;
        #pragma unroll 2
        for (int k4 = 0; k4 < 72; k4 += 4){
          float4 w0 = W04[(k4+0)*32 + lane];
          float4 w1 = W04[(k4+1)*32 + lane];
          float4 w2 = W04[(k4+2)*32 + lane];
          float4 w3 = W04[(k4+3)*32 + lane];
          float4 x0 = *(const float4*)&X[s0+0][k4];
          float4 x1 = *(const float4*)&X[s0+1][k4];
          float4 x2 = *(const float4*)&X[s0+2][k4];
          float4 x3 = *(const float4*)&X[s0+3][k4];
          a0.x+=x0.x*w0.x; a0.y+=x0.x*w0.y; a0.z+=x0.x*w0.z; a0.w+=x0.x*w0.w;
          a1.x+=x1.x*w0.x; a1.y+=x1.x*w0.y; a1.z+=x1.x*w0.z; a1.w+=x1.x*w0.w;
          a2.x+=x2.x*w0.x; a2.y+=x2.x*w0.y; a2.z+=x2.x*w0.z; a2.w+=x2.x*w0.w;
          a3.x+=x3.x*w0.x; a3.y+=x3.x*w0.y; a3.z+=x3.x*w0.z; a3.w+=x3.x*w0.w;
          a0.x+=x0.y*w1.x; a0.y+=x0.y*w1.y; a0.z+=x0.y*w1.z; a0.w+=x0.y*w1.w;
          a1.x+=x1.y*w1.x; a1.y+=x1.y*w1.y; a1.z+=x1.y*w1.z; a1.w+=x1.y*w1.w;
          a2.x+=x2.y*w1.x; a2.y+=x2.y*w1.y; a2.z+=x2.y*w1.z; a2.w+=x2.y*w1.w;
          a3.x+=x3.y*w1.x; a3.y+=x3.y*w1.y; a3.z+=x3.y*w1.z; a3.w+=x3.y*w1.w;
          a0.x+=x0.z*w2.x; a0.y+=x0.z*w2.y; a0.z+=x0.z*w2.z; a0.w+=x0.z*w2.w;
          a1.x+=x1.z*w2.x; a1.y+=x1.z*w2.y; a1.z+=x1.z*w2.z; a1.w+=x1.z*w2.w;
          a2.x+=x2.z*w2.x; a2.y+=x2.z*w2.y; a2.z+=x2.z*w2.z; a2.w+=x2.z*w2.w;
          a3.x+=x3.z*w2.x; a3.y+=x3.z*w2.y; a3.z+=x3.z*w2.z; a3.w+=x3.z*w2.w;
          a0.x+=x0.w*w3.x; a0.y+=x0.w*w3.y; a0.z+=x0.w*w3.z; a0.w+=x0.w*w3.w;
          a1.x+=x1.w*w3.x; a1.y+=x1.w*w3.y; a1.z+=x1.w*w3.z; a1.w+=x1.w*w3.w;
          a2.x+=x2.w*w3.x; a2.y+=x2.w*w3.y; a2.z+=x2.w*w3.z; a2.w+=x2.w*w3.w;
          a3.x+=x3.w*w3.x; a3.y+=x3.w*w3.y; a3.z+=x3.w*w3.z; a3.w+=x3.w*w3.w;
        }
        #pragma unroll
        for (int k = 72; k < 75; k++){
          float4 w = W04[k*32 + lane];
          float x0 = X[s0+0][k], x1 = X[s0+1][k], x2 = X[s0+2][k], x3 = X[s0+3][k];
          a0.x+=x0*w.x; a0.y+=x0*w.y; a0.z+=x0*w.z; a0.w+=x0*w.w;
          a1.x+=x1*w.x; a1.y+=x1*w.y; a1.z+=x1*w.z; a1.w+=x1*w.w;
          a2.x+=x2*w.x; a2.y+=x2*w.y; a2.z+=x2*w.z; a2.w+=x2*w.w;
          a3.x+=x3*w.x; a3.y+=x3*w.y; a3.z+=x3*w.z; a3.w+=x3*w.w;
        }
        H[s0+0][lane*4+0]=fmaxf(a0.x,0.f); H[s0+0][lane*4+1]=fmaxf(a0.y,0.f);
        H[s0+0][lane*4+2]=fmaxf(a0.z,0.f); H[s0+0][lane*4+3]=fmaxf(a0.w,0.f);
        H[s0+1][lane*4+0]=fmaxf(a1.x,0.f); H[s0+1][lane*4+1]=fmaxf(a1.y,0.f);
        H[s0+1][lane*4+2]=fmaxf(a1.z,0.f); H[s0+1][lane*4+3]=fmaxf(a1.w,0.f);
        H[s0+2][lane*4+0]=fmaxf(a2.x,0.f); H[s0+2][lane*4+1]=fmaxf(a2.y,0.f);
        H[s0+2][lane*4+2]=fmaxf(a2.z,0.f); H[s0+2][lane*4+3]=fmaxf(a2.w,0.f);
        H[s0+3][lane*4+0]=fmaxf(a3.x,0.f); H[s0+3][lane*4+1]=fmaxf(a3.y,0.f);
        H[s0+3][lane*4+2]=fmaxf(a3.z,0.f); H[s0+3][lane*4+3]=fmaxf(a3.w,0.f);
      }
      __syncthreads();

      // ---- layer 1: 128 -> 128, batches of 4 k ----
      {
        const float4 bb = ((const float4*)b1)[lane];
        float4 a0 = bb, a1 = bb, a2 = bb, a3 = bb;
        const int s0 = sg*4;
        #pragma unroll 2
        for (int k4 = 0; k4 < 128; k4 += 4){
          float4 w0 = W14[(k4+0)*32 + lane];
          float4 w1 = W14[(k4+1)*32 + lane];
          float4 w2 = W14[(k4+2)*32 + lane];
          float4 w3 = W14[(k4+3)*32 + lane];
          float4 x0 = *(const float4*)&H[s0+0][k4];
          float4 x1 = *(const float4*)&H[s0+1][k4];
          float4 x2 = *(const float4*)&H[s0+2][k4];
          float4 x3 = *(const float4*)&H[s0+3][k4];
          a0.x+=x0.x*w0.x; a0.y+=x0.x*w0.y; a0.z+=x0.x*w0.z; a0.w+=x0.x*w0.w;
          a1.x+=x1.x*w0.x; a1.y+=x1.x*w0.y; a1.z+=x1.x*w0.z; a1.w+=x1.x*w0.w;
          a2.x+=x2.x*w0.x; a2.y+=x2.x*w0.y; a2.z+=x2.x*w0.z; a2.w+=x2.x*w0.w;
          a3.x+=x3.x*w0.x; a3.y+=x3.x*w0.y; a3.z+=x3.x*w0.z; a3.w+=x3.x*w0.w;
          a0.x+=x0.y*w1.x; a0.y+=x0.y*w1.y; a0.z+=x0.y*w1.z; a0.w+=x0.y*w1.w;
          a1.x+=x1.y*w1.x; a1.y+=x1.y*w1.y; a1.z+=x1.y*w1.z; a1.w+=x1.y*w1.w;
          a2.x+=x2.y*w1.x; a2.y+=x2.y*w1.y; a2.z+=x2.y*w1.z; a2.w+=x2.y*w1.w;
          a3.x+=x3.y*w1.x; a3.y+=x3.y*w1.y; a3.z+=x3.y*w1.z; a3.w+=x3.y*w1.w;
          a0.x+=x0.z*w2.x; a0.y+=x0.z*w2.y; a0.z+=x0.z*w2.z; a0.w+=x0.z*w2.w;
          a1.x+=x1.z*w2.x; a1.y+=x1.z*w2.y; a1.z+=x1.z*w2.z; a1.w+=x1.z*w2.w;
          a2.x+=x2.z*w2.x; a2.y+=x2.z*w2.y; a2.z+=x2.z*w2.z; a2.w+=x2.z*w2.w;
          a3.x+=x3.z*w2.x; a3.y+=x3.z*w2.y; a3.z+=x3.z*w2.z; a3.w+=x3.z*w2.w;
          a0.x+=x0.w*w3.x; a0.y+=x0.w*w3.y; a0.z+=x0.w*w3.z; a0.w+=x0.w*w3.w;
          a1.x+=x1.w*w3.x; a1.y+=x1.w*w3.y; a1.z+=x1.w*w3.z; a1.w+=x1.w*w3.w;
          a2.x+=x2.w*w3.x; a2.y+=x2.w*w3.y; a2.z+=x2.w*w3.z; a2.w+=x2.w*w3.w;
          a3.x+=x3.w*w3.x; a3.y+=x3.w*w3.y; a3.z+=x3.w*w3.z; a3.w+=x3.w*w3.w;
        }
        H2[s0+0][lane*4+0]=fmaxf(a0.x,0.f); H2[s0+0][lane*4+1]=fmaxf(a0.y,0.f);
        H2[s0+0][lane*4+2]=fmaxf(a0.z,0.f); H2[s0+0][lane*4+3]=fmaxf(a0.w,0.f);
        H2[s0+1][lane*4+0]=fmaxf(a1.x,0.f); H2[s0+1][lane*4+1]=fmaxf(a1.y,0.f);
        H2[s0+1][lane*4+2]=fmaxf(a1.z,0.f); H2[s0+1][lane*4+3]=fmaxf(a1.w,0.f);
        H2[s0+2][lane*4+0]=fmaxf(a2.x,0.f); H2[s0+2][lane*4+1]=fmaxf(a2.y,0.f);
        H2[s0+2][lane*4+2]=fmaxf(a2.z,0.f); H2[s0+2][lane*4+3]=fmaxf(a2.w,0.f);
        H2[s0+3][lane*4+0]=fmaxf(a3.x,0.f); H2[s0+3][lane*4+1]=fmaxf(a3.y,0.f);
        H2[s0+3][lane*4+2]=fmaxf(a3.z,0.f); H2[s0+3][lane*4+3]=fmaxf(a3.w,0.f);
      }
      __syncthreads();

      // ---- layer 2: 128 -> 3, per sample-group, 32-lane shuffle reduce ----
      {
        const int s0 = sg*4;
        #pragma unroll
        for (int i = 0; i < 4; i++){
          const int s = s0 + i;
          float4 h = *(const float4*)&H2[s][lane*4];
          float c0 = h.x*W2[(lane*4+0)*3+0] + h.y*W2[(lane*4+1)*3+0]
                   + h.z*W2[(lane*4+2)*3+0] + h.w*W2[(lane*4+3)*3+0];
          float c1 = h.x*W2[(lane*4+0)*3+1] + h.y*W2[(lane*4+1)*3+1]
                   + h.z*W2[(lane*4+2)*3+1] + h.w*W2[(lane*4+3)*3+1];
          float c2 = h.x*W2[(lane*4+0)*3+2] + h.y*W2[(lane*4+1)*3+2]
                   + h.z*W2[(lane*4+2)*3+2] + h.w*W2[(lane*4+3)*3+2];
          #pragma unroll
          for (int d=16; d>=1; d>>=1){
            c0 += __shfl_down(c0, d, 32);
            c1 += __shfl_down(c1, d, 32);
            c2 += __shfl_down(c2, d, 32);
          }
          if (lane == 0){
            OUTB[s][0] = sigmf(c0 + b2[0]);
            OUTB[s][1] = sigmf(c1 + b2[1]);
            OUTB[s][2] = sigmf(c2 + b2[2]);
          }
        }
      }
      __syncthreads();

      if (t < 96) {
        int s2 = t/3, c = t - s2*3;
        float w = WSH[s2];
        if (w > 0.0f && (head == 0 || SEM[s2] != 0)) {
          int n2 = SSAMP[s2]/NSTEPS;
          atomicAdd(&out[n2*3 + c], w * OUTB[s2][c]);
        }
      }
    }
    __syncthreads();
  }
}

extern "C" void kernel_launch(void* const* d_in, const int* in_sizes, int n_in,
                              void* d_out, int out_size, void* d_ws, size_t ws_size,
                              hipStream_t stream) {
  const float* ro    = (const float*)d_in[0];
  const float* rd    = (const float*)d_in[1];
  const float* vd    = (const float*)d_in[2];
  const int*   em    = (const int*)d_in[3];
  const float* sdfg  = (const float*)d_in[4];
  const float* maskg = (const float*)d_in[5];
  const float* offc  = (const float*)d_in[6];
  const float* emoc  = (const float*)d_in[7];
  const float* W0o = (const float*)d_in[8];
  const float* b0o = (const float*)d_in[9];
  const float* W1o = (const float*)d_in[10];
  const float* b1o = (const float*)d_in[11];
  const float* W2o = (const float*)d_in[12];
  const float* b2o = (const float*)d_in[13];
  const float* W0e = (const float*)d_in[14];
  const float* b0e = (const float*)d_in[15];
  const float* W1e = (const float*)d_in[16];
  const float* b1e = (const float*)d_in[17];
  const float* W2e = (const float*)d_in[18];
  const float* b2e = (const float*)d_in[19];

  float* out = (float*)d_out;
  float* ws  = (float*)d_ws;
  float* Yb    = ws;                         // GG3 (yz-smoothed)
  float* swb   = ws + GG3;                   // NSAMP
  float* sgradb= swb + NSAMP;                // 3*NSAMP
  int*   slist = (int*)(sgradb + 3*(size_t)NSAMP);  // NSAMP
  int*   cnt   = slist + NSAMP;              // 1

  ksmooth_yz<<<GG*25, 256, 0, stream>>>(sdfg, Yb, out, cnt);

  kmarch<<<NRAYS/64, 64, 0, stream>>>(ro, rd, vd, maskg, Yb,
                                      slist, swb, sgradb, cnt, out);

  kmlp5<<<512, 256, 0, stream>>>(ro, rd, vd, em, offc, emoc,
                                 slist, swb, sgradb, cnt,
                                 W0o,b0o,W1o,b1o,W2o,b2o,
                                 W0e,b0e,W1e,b1e,W2e,b2e, out);
}